// Round 8
// baseline (250.134 us; speedup 1.0000x reference)
//
#include <hip/hip_runtime.h>
#include <hip/hip_bf16.h>

#define NEG_SLOPE 0.2f
#define EPB  8192   // edges per coarse-sort block
#define MAXC 2048   // max coarse bins (= ceil(n_dst/32)); 50000/32 = 1563

typedef __attribute__((ext_vector_type(8))) short bf16x8;
typedef __attribute__((ext_vector_type(4))) float f32x4;

__device__ __forceinline__ float b2f_lo(unsigned u) { return __uint_as_float(u << 16); }
__device__ __forceinline__ float b2f_hi(unsigned u) { return __uint_as_float(u & 0xffff0000u); }

__device__ __forceinline__ short f2b(float x) {
    unsigned u = __float_as_uint(x);
    unsigned r = (u + 0x7fffu + ((u >> 16) & 1u)) >> 16;
    return (short)r;
}

// ---------------------------------------------------------------------------
// 0) Pack W into MFMA B-fragment order (bf16) + fused logit matrix V = W·A'
//    (9th n-tile) and c = b·A'.
// ---------------------------------------------------------------------------
__global__ __launch_bounds__(256) void pack_kernel(
    const float* __restrict__ W_src, const float* __restrict__ W_dst,
    const float* __restrict__ b_src, const float* __restrict__ b_dst,
    const float* __restrict__ attn,  // [8,32]
    uint4* __restrict__ wp_src, uint4* __restrict__ wp_dst,
    float* __restrict__ c_all)       // [16]
{
    const int e = blockIdx.x * 256 + threadIdx.x;
    if (e < 4608) {
        const int which = e / 2304;
        const int e2 = e % 2304;
        const float* W = which ? W_dst : W_src;
        uint4* wp = which ? wp_dst : wp_src;
        const int aoff = which ? 16 : 0;
        short out[8];
        if (e2 < 2048) {                    // W tiles
            const int t = e2 >> 8, q = (e2 >> 6) & 3, l = e2 & 63;
            const int kbase = (l >> 4) * 8 + q * 32;
            const int n = t * 16 + (l & 15);
            #pragma unroll
            for (int j = 0; j < 8; ++j) out[j] = f2b(W[(size_t)(kbase + j) * 128 + n]);
            *(uint4*)&wp[(t * 4 + q) * 64 + l] = *(uint4*)out;
        } else {                            // V tile (fused logits)
            const int e3 = e2 - 2048;
            const int q = e3 >> 6, l = e3 & 63;
            const int kbase = (l >> 4) * 8 + q * 32;
            const int n = l & 15;
            #pragma unroll
            for (int j = 0; j < 8; ++j) {
                float v = 0.f;
                if (n < 8) {
                    for (int dd = 0; dd < 16; ++dd)
                        v += W[(size_t)(kbase + j) * 128 + n * 16 + dd] * attn[n * 32 + aoff + dd];
                }
                out[j] = f2b(v);
            }
            *(uint4*)&wp[(32 + q) * 64 + l] = *(uint4*)out;
        }
    } else if (e < 4624) {                  // c = b·A'
        const int k = e - 4608;
        const int which = k >> 3, kk = k & 7;
        const float* bb = which ? b_dst : b_src;
        const int aoff = which ? 16 : 0;
        float v = 0.f;
        for (int dd = 0; dd < 16; ++dd) v += bb[kk * 16 + dd] * attn[kk * 32 + aoff + dd];
        c_all[k] = v;
    }
}

// ---------------------------------------------------------------------------
// coarse histogram body (LDS, no global atomics): H[bin][block] matrix
// ---------------------------------------------------------------------------
__device__ __forceinline__ void hist_body(
    const int* __restrict__ dst_idx, int* __restrict__ Hmat,
    int nEdges, int nCoarse, int nCB, int bx)
{
    __shared__ int h[MAXC];
    const int t = threadIdx.x;
    for (int i = t; i < nCoarse; i += 256) h[i] = 0;
    __syncthreads();
    const int e0 = bx * EPB;
    const int e1 = min(e0 + EPB, nEdges);
    for (int e = e0 + t; e < e1; e += 256) atomicAdd(&h[dst_idx[e] >> 5], 1);
    __syncthreads();
    for (int i = t; i < nCoarse; i += 256) Hmat[(size_t)i * nCB + bx] = h[i];
}

// ---------------------------------------------------------------------------
// MFMA projection body: h = feat·W + b (bf16 in, fp32 acc), fused logit via
// 9th n-tile. Wave = 2 m-tiles (32 rows); block = 128 rows.
// ---------------------------------------------------------------------------
template<bool STORE_H>
__device__ __forceinline__ void proj_body(
    const float* __restrict__ feat, const uint4* __restrict__ wp,
    const float* __restrict__ b, const float* __restrict__ cvec,
    short* __restrict__ hs_out, float* __restrict__ el_out,
    int N, int bx)
{
    const int t = threadIdx.x;
    const int lane = t & 63;
    const int w = t >> 6;
    const int m  = lane & 15;
    const int q8 = lane >> 4;
    const int row0 = bx * 128 + w * 32;

    f32x4 acc0[9], acc1[9];
    #pragma unroll
    for (int tt = 0; tt < 8; ++tt) {
        const float bn = b[tt * 16 + m];
        acc0[tt] = (f32x4){bn, bn, bn, bn};
        acc1[tt] = (f32x4){bn, bn, bn, bn};
    }
    acc0[8] = (f32x4){0.f, 0.f, 0.f, 0.f};
    acc1[8] = (f32x4){0.f, 0.f, 0.f, 0.f};

    int rowA0 = row0 + m;      if (rowA0 >= N) rowA0 = N - 1;
    int rowA1 = row0 + 16 + m; if (rowA1 >= N) rowA1 = N - 1;
    const float* f0 = feat + (size_t)rowA0 * 128 + q8 * 8;
    const float* f1 = feat + (size_t)rowA1 * 128 + q8 * 8;
    const bf16x8* wpv = (const bf16x8*)wp;

    #pragma unroll
    for (int kc = 0; kc < 4; ++kc) {
        const float4 fa0 = *(const float4*)(f0 + kc * 32);
        const float4 fb0 = *(const float4*)(f0 + kc * 32 + 4);
        const float4 fa1 = *(const float4*)(f1 + kc * 32);
        const float4 fb1 = *(const float4*)(f1 + kc * 32 + 4);
        bf16x8 a0, a1;
        a0[0]=f2b(fa0.x); a0[1]=f2b(fa0.y); a0[2]=f2b(fa0.z); a0[3]=f2b(fa0.w);
        a0[4]=f2b(fb0.x); a0[5]=f2b(fb0.y); a0[6]=f2b(fb0.z); a0[7]=f2b(fb0.w);
        a1[0]=f2b(fa1.x); a1[1]=f2b(fa1.y); a1[2]=f2b(fa1.z); a1[3]=f2b(fa1.w);
        a1[4]=f2b(fb1.x); a1[5]=f2b(fb1.y); a1[6]=f2b(fb1.z); a1[7]=f2b(fb1.w);
        #pragma unroll
        for (int tt = 0; tt < 8; ++tt) {
            const bf16x8 bf = wpv[(tt * 4 + kc) * 64 + lane];
            acc0[tt] = __builtin_amdgcn_mfma_f32_16x16x32_bf16(a0, bf, acc0[tt], 0, 0, 0);
            acc1[tt] = __builtin_amdgcn_mfma_f32_16x16x32_bf16(a1, bf, acc1[tt], 0, 0, 0);
        }
        {
            const bf16x8 bv = wpv[(32 + kc) * 64 + lane];
            acc0[8] = __builtin_amdgcn_mfma_f32_16x16x32_bf16(a0, bv, acc0[8], 0, 0, 0);
            acc1[8] = __builtin_amdgcn_mfma_f32_16x16x32_bf16(a1, bv, acc1[8], 0, 0, 0);
        }
    }

    #pragma unroll
    for (int half = 0; half < 2; ++half) {
        const f32x4* acc = half ? acc1 : acc0;
        const int rbase = row0 + half * 16 + q8 * 4;
        #pragma unroll
        for (int reg = 0; reg < 4; ++reg) {
            const int row = rbase + reg;
            if (row < N) {
                if (STORE_H) {
                    #pragma unroll
                    for (int tt = 0; tt < 8; ++tt)
                        hs_out[(size_t)row * 128 + tt * 16 + m] = f2b(acc[tt][reg]);
                }
                if (m < 8) el_out[(size_t)row * 8 + m] = acc[8][reg] + cvec[m];
            }
        }
    }
}

// ---------------------------------------------------------------------------
// 1) fused: coarse histogram + both MFMA projections (disjoint pipes).
// ---------------------------------------------------------------------------
__global__ __launch_bounds__(256, 2) void fused_proj_hist_kernel(
    const float* __restrict__ feat_src, const float* __restrict__ feat_dst,
    const uint4* __restrict__ wp_src, const uint4* __restrict__ wp_dst,
    const float* __restrict__ b_src, const float* __restrict__ b_dst,
    const float* __restrict__ c_all,
    short* __restrict__ hs, float* __restrict__ el, float* __restrict__ er,
    const int* __restrict__ dst_idx, int* __restrict__ Hmat,
    int n_src, int n_dst, int nEdges, int nCoarse, int nCB, int pSrcBlocks)
{
    int bx = blockIdx.x;
    if (bx < nCB) { hist_body(dst_idx, Hmat, nEdges, nCoarse, nCB, bx); return; }
    bx -= nCB;
    if (bx < pSrcBlocks) {
        proj_body<true>(feat_src, wp_src, b_src, c_all, hs, el, n_src, bx);
        return;
    }
    bx -= pSrcBlocks;
    proj_body<false>(feat_dst, wp_dst, b_dst, c_all + 8, nullptr, er, n_dst, bx);
}

// ---------------------------------------------------------------------------
// 2a) partial sums per 1024-block over flat array
// ---------------------------------------------------------------------------
__global__ __launch_bounds__(1024) void scan_part_kernel(
    const int* __restrict__ cnt, int* __restrict__ part, int n)
{
    __shared__ int wsum[16];
    const int t = threadIdx.x;
    const int i = blockIdx.x * 1024 + t;
    int v = (i < n) ? cnt[i] : 0;
    #pragma unroll
    for (int s = 32; s > 0; s >>= 1) v += __shfl_down(v, s, 64);
    if ((t & 63) == 0) wsum[t >> 6] = v;
    __syncthreads();
    if (t < 16) {
        int x = wsum[t];
        #pragma unroll
        for (int s = 8; s > 0; s >>= 1) x += __shfl_down(x, s, 64);
        if (t == 0) part[blockIdx.x] = x;
    }
}

// ---------------------------------------------------------------------------
// 2b) single-block exclusive scan of partials; S[n] = total
// ---------------------------------------------------------------------------
__global__ __launch_bounds__(1024) void scan_top_kernel(
    int* __restrict__ part, int* __restrict__ S, int nPart, int n)
{
    __shared__ int buf[1024];
    const int t = threadIdx.x;
    const int v = (t < nPart) ? part[t] : 0;
    buf[t] = v;
    __syncthreads();
    #pragma unroll
    for (int s = 1; s < 1024; s <<= 1) {
        const int add = (t >= s) ? buf[t - s] : 0;
        __syncthreads();
        buf[t] += add;
        __syncthreads();
    }
    if (t < nPart) part[t] = buf[t] - v;        // exclusive
    if (t == 1023) S[n] = buf[1023];            // total
}

// ---------------------------------------------------------------------------
// 2c) per-block local exclusive scan + base -> S
// ---------------------------------------------------------------------------
__global__ __launch_bounds__(1024) void scan_local_kernel(
    const int* __restrict__ cnt, const int* __restrict__ part,
    int* __restrict__ S, int n)
{
    __shared__ int buf[1024];
    const int t = threadIdx.x;
    const int i = blockIdx.x * 1024 + t;
    const int v = (i < n) ? cnt[i] : 0;
    buf[t] = v;
    __syncthreads();
    #pragma unroll
    for (int s = 1; s < 1024; s <<= 1) {
        const int add = (t >= s) ? buf[t - s] : 0;
        __syncthreads();
        buf[t] += add;
        __syncthreads();
    }
    if (i < n) S[i] = part[blockIdx.x] + buf[t] - v;
}

// ---------------------------------------------------------------------------
// 3) coarse scatter: LDS-rank scatter of packed (src<<5 | dst&31).
// ---------------------------------------------------------------------------
__global__ __launch_bounds__(256) void coarse_scatter_kernel(
    const int* __restrict__ src_idx, const int* __restrict__ dst_idx,
    const int* __restrict__ S, int* __restrict__ coarse,
    int nEdges, int nCoarse, int nCB)
{
    __shared__ int base_s[MAXC];
    __shared__ int cur_s[MAXC];
    const int t = threadIdx.x, bx = blockIdx.x;
    for (int i = t; i < nCoarse; i += 256) {
        base_s[i] = S[(size_t)i * nCB + bx];
        cur_s[i]  = 0;
    }
    __syncthreads();
    const int e0 = bx * EPB;
    const int e1 = min(e0 + EPB, nEdges);
    for (int e = e0 + t; e < e1; e += 256) {
        const int d = dst_idx[e];
        const int s = src_idx[e];
        const int bin = d >> 5;
        const int lr = atomicAdd(&cur_s[bin], 1);
        coarse[base_s[bin] + lr] = (s << 5) | (d & 31);
    }
}

// ---------------------------------------------------------------------------
// 4) fine sort: one block per coarse bin (32 dsts), LDS counting sort.
// ---------------------------------------------------------------------------
__global__ __launch_bounds__(256) void fine_sort_kernel(
    const int* __restrict__ coarse, const int* __restrict__ S,
    int* __restrict__ off, int* __restrict__ sorted_src,
    int nEdges, int n_dst, int nCoarse, int nCB)
{
    __shared__ int h[32];
    __shared__ int cu[32];
    const int t = threadIdx.x, c = blockIdx.x;
    const int base = S[(size_t)c * nCB];
    const int endp = (c + 1 < nCoarse) ? S[(size_t)(c + 1) * nCB] : nEdges;
    if (t < 32) h[t] = 0;
    __syncthreads();
    for (int i = base + t; i < endp; i += 256) atomicAdd(&h[coarse[i] & 31], 1);
    __syncthreads();
    if (t == 0) {
        int run = 0;
        #pragma unroll
        for (int j = 0; j < 32; ++j) {
            cu[j] = run;
            const int d = c * 32 + j;
            if (d < n_dst) off[d] = base + run;
            run += h[j];
        }
    }
    __syncthreads();
    for (int i = base + t; i < endp; i += 256) {
        const int v = coarse[i];
        const int p = atomicAdd(&cu[v & 31], 1);
        sorted_src[base + p] = v >> 5;
    }
    if (c == 0 && t == 0) off[n_dst] = nEdges;
}

// ---------------------------------------------------------------------------
// 5) reduce: one wave per dst, FULL wave per edge (lane owns 2 channels).
//    Edge indices batch-preloaded (64 at a time, one coalesced load), then
//    broadcast to SGPR via readlane -> hs/el addresses are SALU work with
//    fixed per-lane voffsets; no dependent per-iteration index gather.
// ---------------------------------------------------------------------------
__global__ __launch_bounds__(256) void reduce_kernel(
    const int* __restrict__ sorted_src, const int* __restrict__ off,
    const unsigned short* __restrict__ hs, // [N_src,128] bf16 bits
    const float* __restrict__ el,     // [N_src,8]
    const float* __restrict__ er,     // [N_dst,8]
    float* __restrict__ out,          // [N_dst,128]
    int n_dst)
{
    const int wid = blockIdx.x * 4 + (threadIdx.x >> 6);
    if (wid >= n_dst) return;
    const int lane = threadIdx.x & 63;
    const int c0 = lane << 1;         // channels c0, c0+1 (same head)
    const int k  = lane >> 3;         // head
    const float erk = er[(size_t)wid * 8 + k];
    const int beg = off[wid], end = off[wid + 1];

    float a0 = 0.f, a1 = 0.f, es = 0.f;
    for (int base = beg; base < end; base += 64) {
        const int cnt = min(64, end - base);
        int bi = base + lane; if (bi >= end) bi = end - 1;
        const int myidx = sorted_src[bi];
        int j = 0;
        for (; j + 2 <= cnt; j += 2) {
            const int sA = __builtin_amdgcn_readlane(myidx, j);
            const int sB = __builtin_amdgcn_readlane(myidx, j + 1);
            const float lA = el[(size_t)sA * 8 + k];
            const float lB = el[(size_t)sB * 8 + k];
            const unsigned uA = *(const unsigned*)(hs + (size_t)sA * 128 + c0);
            const unsigned uB = *(const unsigned*)(hs + (size_t)sB * 128 + c0);
            float xA = lA + erk; xA = (xA >= 0.f) ? xA : NEG_SLOPE * xA;
            float xB = lB + erk; xB = (xB >= 0.f) ? xB : NEG_SLOPE * xB;
            const float eA = __expf(xA);
            const float eB = __expf(xB);
            es += eA + eB;
            a0 = fmaf(eA, b2f_lo(uA), a0); a1 = fmaf(eA, b2f_hi(uA), a1);
            a0 = fmaf(eB, b2f_lo(uB), a0); a1 = fmaf(eB, b2f_hi(uB), a1);
        }
        if (j < cnt) {
            const int s = __builtin_amdgcn_readlane(myidx, j);
            const float l = el[(size_t)s * 8 + k];
            const unsigned u = *(const unsigned*)(hs + (size_t)s * 128 + c0);
            float x = l + erk; x = (x >= 0.f) ? x : NEG_SLOPE * x;
            const float ee = __expf(x);
            es += ee;
            a0 = fmaf(ee, b2f_lo(u), a0); a1 = fmaf(ee, b2f_hi(u), a1);
        }
    }
    const float inv = (es > 0.f) ? 1.f / es : 0.f;
    float2 o; o.x = a0 * inv; o.y = a1 * inv;
    *(float2*)(out + (size_t)wid * 128 + c0) = o;
}

extern "C" void kernel_launch(void* const* d_in, const int* in_sizes, int n_in,
                              void* d_out, int out_size, void* d_ws, size_t ws_size,
                              hipStream_t stream) {
    const float* feat_src = (const float*)d_in[0];
    const float* feat_dst = (const float*)d_in[1];
    const float* W_src    = (const float*)d_in[2];
    const float* b_src    = (const float*)d_in[3];
    const float* W_dst    = (const float*)d_in[4];
    const float* b_dst    = (const float*)d_in[5];
    const float* attn     = (const float*)d_in[6];
    const int*   src_idx  = (const int*)d_in[7];
    const int*   dst_idx  = (const int*)d_in[8];
    float* out = (float*)d_out;

    const int n_src  = in_sizes[0] / 128;
    const int n_dst  = in_sizes[1] / 128;
    const int nEdges = in_sizes[7];

    const int nCoarse = (n_dst + 31) >> 5;                 // 1563
    const int nCB     = (nEdges + EPB - 1) / EPB;          // 196
    const int nH      = nCoarse * nCB;                     // ~306k
    const int nPart   = (nH + 1023) / 1024;                // ~300
    const int pSrc    = (n_src + 127) / 128;
    const int pDst    = (n_dst + 127) / 128;

    // workspace layout
    __hip_bfloat16* hs = (__hip_bfloat16*)d_ws;            // n_src*128 bf16
    float* el   = (float*)(hs + (size_t)n_src * 128);      // n_src*8
    float* er   = el + (size_t)n_src * 8;                  // n_dst*8
    int*   off  = (int*)(er + (size_t)n_dst * 8);          // n_dst+1 (+pad)
    int*   part = off + n_dst + 4;                         // <=1024
    int*   Hmat = part + 1024;                             // nH
    int*   Sarr = Hmat + nH;                               // nH+1 (+pad)
    int*   coarse = Sarr + nH + 4;                         // nEdges (packed)
    int*   sorted_src = coarse + nEdges;                   // nEdges
    uintptr_t p = (uintptr_t)(sorted_src + nEdges);
    p = (p + 15) & ~(uintptr_t)15;
    uint4* wp_src = (uint4*)p;                             // 36*64 uint4
    uint4* wp_dst = wp_src + 36 * 64;                      // 36*64 uint4
    float* c_all  = (float*)(wp_dst + 36 * 64);            // 16 floats

    pack_kernel<<<19, 256, 0, stream>>>(W_src, W_dst, b_src, b_dst, attn,
                                        wp_src, wp_dst, c_all);

    fused_proj_hist_kernel<<<nCB + pSrc + pDst, 256, 0, stream>>>(
        feat_src, feat_dst, wp_src, wp_dst, b_src, b_dst, c_all,
        (short*)hs, el, er, dst_idx, Hmat,
        n_src, n_dst, nEdges, nCoarse, nCB, pSrc);

    scan_part_kernel<<<nPart, 1024, 0, stream>>>(Hmat, part, nH);
    scan_top_kernel<<<1, 1024, 0, stream>>>(part, Sarr, nPart, nH);
    scan_local_kernel<<<nPart, 1024, 0, stream>>>(Hmat, part, Sarr, nH);

    coarse_scatter_kernel<<<nCB, 256, 0, stream>>>(src_idx, dst_idx, Sarr,
                                                   coarse, nEdges, nCoarse, nCB);
    fine_sort_kernel<<<nCoarse, 256, 0, stream>>>(coarse, Sarr, off, sorted_src,
                                                  nEdges, n_dst, nCoarse, nCB);

    reduce_kernel<<<(n_dst + 3) / 4, 256, 0, stream>>>(sorted_src, off,
        (const unsigned short*)hs, el, er, out, n_dst);
}